// Round 7
// baseline (388.593 us; speedup 1.0000x reference)
//
#include <hip/hip_runtime.h>

// Problem constants
#define B_ 128
#define T_ 256
#define F_ 1024
#define C_ 512
#define K_ F_

typedef _Float16 f16;
typedef f16 f16x8 __attribute__((ext_vector_type(8)));
typedef float f32x4 __attribute__((ext_vector_type(4)));

// ---------------------------------------------------------------------------
// W split + transpose: W[K][N] f32 -> WhiT[N][K] f16, WloT[N][K] f16 (x4096)
// ---------------------------------------------------------------------------
__global__ __launch_bounds__(256) void wsplit_kernel(
    const float* __restrict__ W, f16* __restrict__ WhiT,
    f16* __restrict__ WloT) {
  __shared__ float tile[32][33];
  const int k0 = blockIdx.x * 32;
  const int n0 = blockIdx.y * 32;
  const int tid = threadIdx.x;
#pragma unroll
  for (int j = 0; j < 4; ++j) {
    const int e = tid + 256 * j;
    const int r = e >> 5, c = e & 31;
    tile[r][c] = W[(size_t)(k0 + r) * C_ + n0 + c];
  }
  __syncthreads();
#pragma unroll
  for (int j = 0; j < 4; ++j) {
    const int e = tid + 256 * j;
    const int nn = e >> 5, kk = e & 31;
    const float w = tile[kk][nn];
    const f16 wh = (f16)w;
    const f16 wl = (f16)((w - (float)wh) * 4096.0f);
    WhiT[(size_t)(n0 + nn) * K_ + k0 + kk] = wh;
    WloT[(size_t)(n0 + nn) * K_ + k0 + kk] = wl;
  }
}

// ---------------------------------------------------------------------------
// Fused MFMA GEMM: I = Xhi@Whi + 2^-12 (Xlo@Whi + Xhi@Wlo)
// R7: 256x128 block tile, 512 threads / 8 waves (2n x 4m of 64x64 wave tiles),
// 16x16x32 f16 MFMA, BK=32. Per-thread B staging halved vs 128x128; occupancy
// 16 waves/CU (LDS 60KB -> 2 blocks/CU). Wave-tile fragment mappings unchanged.
// ---------------------------------------------------------------------------
#define LDT 40  // padded row length in f16 (80B = 5 x 16B slots, conflict-light)

__global__ __launch_bounds__(512) void snn_gemm_mfma(
    const float* __restrict__ X, const f16* __restrict__ WhiT,
    const f16* __restrict__ WloT, float* __restrict__ I) {
  __shared__ f16 sAh[256 * LDT];  // 20KB
  __shared__ f16 sAl[256 * LDT];  // 20KB
  __shared__ f16 sBh[128 * LDT];  // 10KB
  __shared__ f16 sBl[128 * LDT];  // 10KB

  const int tid = threadIdx.x;
  const int m0 = blockIdx.x * 256;
  const int n0 = blockIdx.y * 128;
  const int lane = tid & 63;
  const int w = tid >> 6;                      // 0..7
  const int wm = (w >> 1) * 64, wn = (w & 1) * 64;

  // Staging: A rows tid>>2 and (tid>>2)+128, 8 f32 each at col (tid&3)*8;
  //          B row tid>>2, 8 f16 each from WhiT and WloT at col (tid&3)*8.
  const int rA = tid >> 2, c8 = (tid & 3) * 8;
  const float* gA0 = X + (size_t)(m0 + rA) * K_ + c8;
  const float* gA1 = X + (size_t)(m0 + rA + 128) * K_ + c8;
  const f16* gBh = WhiT + (size_t)(n0 + rA) * K_ + c8;  // rA<128 rows of B
  const f16* gBl = WloT + (size_t)(n0 + rA) * K_ + c8;
  const int wrA0 = rA * LDT + c8;
  const int wrA1 = (rA + 128) * LDT + c8;
  const int wrB = rA * LDT + c8;

  float4 xa0, xa1, xb0, xb1;
  uint4 vBh, vBl;
  f16x8 Ah0, Al0, Ah1, Al1;

#define SPLIT8(p0, p1, H, L)                                   \
  {                                                            \
    const float v_[8] = {(p0).x, (p0).y, (p0).z, (p0).w,       \
                         (p1).x, (p1).y, (p1).z, (p1).w};      \
    _Pragma("unroll") for (int j_ = 0; j_ < 8; ++j_) {         \
      const f16 h_ = (f16)v_[j_];                              \
      (H)[j_] = h_;                                            \
      (L)[j_] = (f16)((v_[j_] - (float)h_) * 4096.0f);         \
    }                                                          \
  }

  // prologue: load + convert tile 0
  xa0 = *(const float4*)(gA0);
  xa1 = *(const float4*)(gA0 + 4);
  xb0 = *(const float4*)(gA1);
  xb1 = *(const float4*)(gA1 + 4);
  vBh = *(const uint4*)(gBh);
  vBl = *(const uint4*)(gBl);
  SPLIT8(xa0, xa1, Ah0, Al0);
  SPLIT8(xb0, xb1, Ah1, Al1);

  f32x4 acc0[4][4] = {};
  f32x4 acc1[4][4] = {};

  for (int kt = 0; kt < K_ / 32; ++kt) {
    __syncthreads();
    *(f16x8*)&sAh[wrA0] = Ah0;
    *(f16x8*)&sAh[wrA1] = Ah1;
    *(f16x8*)&sAl[wrA0] = Al0;
    *(f16x8*)&sAl[wrA1] = Al1;
    *(uint4*)&sBh[wrB] = vBh;
    *(uint4*)&sBl[wrB] = vBl;
    __syncthreads();
    const bool more = (kt + 1 < K_ / 32);
    if (more) {
      const int ko = (kt + 1) * 32;
      xa0 = *(const float4*)(gA0 + ko);
      xa1 = *(const float4*)(gA0 + ko + 4);
      xb0 = *(const float4*)(gA1 + ko);
      xb1 = *(const float4*)(gA1 + ko + 4);
      vBh = *(const uint4*)(gBh + ko);
      vBl = *(const uint4*)(gBl + ko);
    }
    const int lrow = lane & 15;
    const int sl = (lane >> 4) * 8;
    f16x8 Bh[4], Bl[4];
#pragma unroll
    for (int fn = 0; fn < 4; ++fn) {
      const int nrow = (wn + fn * 16 + lrow) * LDT + sl;
      Bh[fn] = *(const f16x8*)&sBh[nrow];
      Bl[fn] = *(const f16x8*)&sBl[nrow];
    }
#pragma unroll
    for (int fm = 0; fm < 4; ++fm) {
      const int mrow = (wm + fm * 16 + lrow) * LDT + sl;
      const f16x8 Ah = *(const f16x8*)&sAh[mrow];
      const f16x8 Al = *(const f16x8*)&sAl[mrow];
#pragma unroll
      for (int fn = 0; fn < 4; ++fn) {
        acc0[fm][fn] = __builtin_amdgcn_mfma_f32_16x16x32_f16(
            Ah, Bh[fn], acc0[fm][fn], 0, 0, 0);
        acc1[fm][fn] = __builtin_amdgcn_mfma_f32_16x16x32_f16(
            Al, Bh[fn], acc1[fm][fn], 0, 0, 0);
        acc1[fm][fn] = __builtin_amdgcn_mfma_f32_16x16x32_f16(
            Ah, Bl[fn], acc1[fm][fn], 0, 0, 0);
      }
    }
    if (more) {
      SPLIT8(xa0, xa1, Ah0, Al0);
      SPLIT8(xb0, xb1, Ah1, Al1);
    }
  }

  // Epilogue: D row = 4*(lane>>4)+i, col = lane&15 ; combine the two scales.
  const int er = (lane >> 4) * 4;
  const int ec = lane & 15;
#pragma unroll
  for (int fm = 0; fm < 4; ++fm)
#pragma unroll
    for (int fn = 0; fn < 4; ++fn) {
      float* op =
          I + (size_t)(m0 + wm + fm * 16 + er) * C_ + n0 + wn + fn * 16 + ec;
#pragma unroll
      for (int i = 0; i < 4; ++i)
        op[(size_t)i * C_] = acc0[fm][fn][i] + acc1[fm][fn][i] * (1.0f / 4096.0f);
    }
}

// ---------------------------------------------------------------------------
// Scan v3 (byte-identical to R6 — launched TWICE this round to measure its
// duration by subtraction: total_R7 - gemm_R7 - (total_R6 - gemm_R6) = scan).
// ---------------------------------------------------------------------------
#define TTS 32

#define STEP(Iv)                                                           \
  {                                                                        \
    const bool is0 = (mode == 0), is1 = (mode == 1), is2 = (mode == 2);    \
    V = is0 ? ((V + (Iv)) - 0.01f) : (is2 ? (V + 0.01f) : V);              \
    V = fmaxf(V, 0.0f);                                                    \
    const bool fired = is0 && ((V - 0.4f) > 0.0f);                         \
    sc += fired ? 1.0f : 0.0f;                                             \
    refr = fired ? 2.0f : (is1 ? fmaxf(refr - 1.0f, 0.0f) : refr);         \
    const bool done = is1 && (refr <= 0.0f);                               \
    const bool back = is2 && (V > 0.0f);                                   \
    V = fired ? 0.0f : V;                                                  \
    mode = fired ? 1 : (done ? 2 : (back ? 0 : mode));                     \
  }

__global__ __launch_bounds__(128) void snn_scan_kernel(
    const float* __restrict__ I, float* __restrict__ out) {
  __shared__ float tile[TTS * 128];  // 16KB
  const int tid = threadIdx.x;
  const int bid = blockIdx.x;
  const int b = bid >> 2;
  const int c0 = (bid & 3) << 7;
  const float* Ib = I + (size_t)b * T_ * C_ + c0;

  float V = 0.f, refr = 0.f, sc = 0.f;
  int mode = 0;

  float4 st[8];
#pragma unroll
  for (int i = 0; i < 8; ++i) {
    const int f4 = i * 128 + tid;
    const int row = f4 >> 5, c4 = f4 & 31;
    st[i] = *(const float4*)(Ib + (size_t)row * C_ + c4 * 4);
  }

  for (int tg = 0; tg < T_ / TTS; ++tg) {
    __syncthreads();
#pragma unroll
    for (int i = 0; i < 8; ++i) {
      const int f4 = i * 128 + tid;
      *(float4*)&tile[f4 * 4] = st[i];
    }
    __syncthreads();
    if (tg + 1 < T_ / TTS) {
      const float* p = Ib + (size_t)(tg + 1) * TTS * C_;
#pragma unroll
      for (int i = 0; i < 8; ++i) {
        const int f4 = i * 128 + tid;
        const int row = f4 >> 5, c4 = f4 & 31;
        st[i] = *(const float4*)(p + (size_t)row * C_ + c4 * 4);
      }
    }
#pragma unroll
    for (int tt = 0; tt < TTS; ++tt) {
      const float Iv = tile[tt * 128 + tid];
      STEP(Iv);
    }
  }
  out[(size_t)b * C_ + c0 + tid] = sc;
}

// ---------------------------------------------------------------------------
extern "C" void kernel_launch(void* const* d_in, const int* in_sizes, int n_in,
                              void* d_out, int out_size, void* d_ws,
                              size_t ws_size, hipStream_t stream) {
  const float* X = (const float*)d_in[0];   // [B_*T_][F_]
  const float* Wm = (const float*)d_in[1];  // [F_, C_]
  float* out = (float*)d_out;               // [B_, C_]

  char* p = (char*)d_ws;
  float* Ibuf = (float*)p; p += (size_t)B_ * T_ * C_ * sizeof(float);
  f16* WhiT = (f16*)p; p += (size_t)C_ * K_ * sizeof(f16);
  f16* WloT = (f16*)p;

  wsplit_kernel<<<dim3(K_ / 32, C_ / 32), 256, 0, stream>>>(Wm, WhiT, WloT);
  snn_gemm_mfma<<<dim3(B_ * T_ / 256, C_ / 128), 512, 0, stream>>>(
      X, WhiT, WloT, Ibuf);
  // Launched twice on purpose (idempotent): scan duration = Δtotal - Δgemm
  // vs R6, pinning down the invisible non-GEMM residual.
  snn_scan_kernel<<<B_ * C_ / 128, 128, 0, stream>>>(Ibuf, out);
  snn_scan_kernel<<<B_ * C_ / 128, 128, 0, stream>>>(Ibuf, out);
}